// Round 3
// baseline (56.988 us; speedup 1.0000x reference)
//
#include <hip/hip_runtime.h>
#include <math.h>

#define NCELL (32768 * 49)   // BATCH * S*S = 1,605,632
#define NE 30
#define NC 20                // classes
#define G1 2048
#define BLK 256
#define TTOT (G1 * BLK)      // 524,288 threads; 4 cells per thread (last k partial)

// partial layout per block: [resp_sum, bce_sum, sqxy_sum, sqwh_sum, nll_sum, coord_sum]

__device__ __forceinline__ void process_cell(
    const float* __restrict__ pred, const float* __restrict__ targ, int cell,
    float& a0, float& a1, float& a2, float& a3, float& a4, float& a5) {

    const float2* p2 = reinterpret_cast<const float2*>(pred + (size_t)cell * NE);
    const float2* t2 = reinterpret_cast<const float2*>(targ + (size_t)cell * NE);

    float p[30], t[12];
    #pragma unroll
    for (int i = 0; i < 15; ++i) { float2 v = p2[i]; p[2*i] = v.x; p[2*i+1] = v.y; }
    #pragma unroll
    for (int i = 0; i < 6; ++i)  { float2 v = t2[i]; t[2*i] = v.x; t[2*i+1] = v.y; }

    // 2x2 cross IoU between pred boxes (rows) and target boxes (cols)
    float iou[2][2];
    #pragma unroll
    for (int i = 0; i < 2; ++i) {
        const float pcx = p[5*i], pcy = p[5*i+1], pw = p[5*i+2], ph = p[5*i+3];
        const float alx = pcx - pw*0.5f, aly = pcy - ph*0.5f;
        const float ahx = pcx + pw*0.5f, ahy = pcy + ph*0.5f;
        const float area_a = pw * ph;
        #pragma unroll
        for (int j = 0; j < 2; ++j) {
            const float tcx = t[5*j], tcy = t[5*j+1], tw = t[5*j+2], th = t[5*j+3];
            const float blx = tcx - tw*0.5f, bly = tcy - th*0.5f;
            const float bhx = tcx + tw*0.5f, bhy = tcy + th*0.5f;
            float ix = fminf(ahx, bhx) - fmaxf(alx, blx);
            float iy = fminf(ahy, bhy) - fmaxf(aly, bly);
            ix = fmaxf(ix, 0.f); iy = fmaxf(iy, 0.f);
            const float inter = ix * iy;
            const float area_b = tw * th;
            iou[i][j] = inter / (area_a + area_b - inter + 1e-12f);
        }
    }
    // argmax over pred-box axis, first-occurrence tie break (index 0)
    const int idx0 = (iou[1][0] > iou[0][0]) ? 1 : 0;
    const int idx1 = (iou[1][1] > iou[0][1]) ? 1 : 0;

    #pragma unroll
    for (int k = 0; k < 2; ++k) {
        const bool resp = (idx0 == k || idx1 == k);
        if (resp) {
            a0 += 1.f;
            const float cp = p[5*k+4], ct = t[5*k+4];
            // logaddexp(0, cp) - cp*ct  (stable)
            a1 += fmaxf(cp, 0.f) + log1pf(expf(-fabsf(cp))) - cp * ct;
            const float dx = p[5*k]   - t[5*k];
            const float dy = p[5*k+1] - t[5*k+1];
            a2 += dx*dx + dy*dy;
            const float dw = p[5*k+2] - t[5*k+2];
            const float dh = p[5*k+3] - t[5*k+3];
            a3 += dw*dw + dh*dh;
        }
    }

    a5 += 1.f;
    // class index: clip(floor(t10), 0, 19)  (clip in float, then cast)
    const float cf = fminf(fmaxf(floorf(t[10]), 0.f), 19.f);
    const int cls = (int)cf;
    float m = p[10];
    #pragma unroll
    for (int c = 1; c < NC; ++c) m = fmaxf(m, p[10 + c]);
    float se = 0.f;
    float sel = 0.f;   // p[10+cls] via static-index select (no scratch)
    #pragma unroll
    for (int c = 0; c < NC; ++c) {
        se += expf(p[10 + c] - m);
        sel += (c == cls) ? p[10 + c] : 0.f;
    }
    a4 += -(sel - m - logf(se));
}

__global__ __launch_bounds__(BLK) void yolo_partial(
    const float* __restrict__ pred,
    const float* __restrict__ targ,
    float* __restrict__ partial) {

    float a0 = 0.f, a1 = 0.f, a2 = 0.f, a3 = 0.f, a4 = 0.f, a5 = 0.f;

    const int tid = blockIdx.x * BLK + threadIdx.x;

    // Batch all 4 strided t4 loads upfront -> 4 outstanding scan loads per
    // lane (MLP), no dependent load->branch->load chain.
    // k=0..2 always in range (3*TTOT + tid < is not guaranteed for k=2? yes:
    // tid + 2*TTOT <= 524287 + 1048576 = 1572863 < NCELL). k=3 partial.
    float t4v[4];
    t4v[0] = targ[(size_t)(tid)            * NE + 4];
    t4v[1] = targ[(size_t)(tid + TTOT)     * NE + 4];
    t4v[2] = targ[(size_t)(tid + 2 * TTOT) * NE + 4];
    t4v[3] = (tid + 3 * TTOT < NCELL) ? targ[(size_t)(tid + 3 * TTOT) * NE + 4] : 0.f;

    if (t4v[0] > 0.f) process_cell(pred, targ, tid,            a0, a1, a2, a3, a4, a5);
    if (t4v[1] > 0.f) process_cell(pred, targ, tid + TTOT,     a0, a1, a2, a3, a4, a5);
    if (t4v[2] > 0.f) process_cell(pred, targ, tid + 2 * TTOT, a0, a1, a2, a3, a4, a5);
    if (t4v[3] > 0.f) process_cell(pred, targ, tid + 3 * TTOT, a0, a1, a2, a3, a4, a5);

    // wave (64-lane) tree reduction
    #pragma unroll
    for (int off = 32; off > 0; off >>= 1) {
        a0 += __shfl_down(a0, off, 64);
        a1 += __shfl_down(a1, off, 64);
        a2 += __shfl_down(a2, off, 64);
        a3 += __shfl_down(a3, off, 64);
        a4 += __shfl_down(a4, off, 64);
        a5 += __shfl_down(a5, off, 64);
    }

    __shared__ float sm[4][6];  // 4 waves per 256-thread block
    const int wave = threadIdx.x >> 6;
    const int lane = threadIdx.x & 63;
    if (lane == 0) {
        sm[wave][0] = a0; sm[wave][1] = a1; sm[wave][2] = a2;
        sm[wave][3] = a3; sm[wave][4] = a4; sm[wave][5] = a5;
    }
    __syncthreads();
    if (threadIdx.x == 0) {
        #pragma unroll
        for (int k = 0; k < 6; ++k) {
            // fixed-order sum over the 4 waves -> deterministic
            float s = sm[0][k] + sm[1][k] + sm[2][k] + sm[3][k];
            partial[blockIdx.x * 6 + k] = s;
        }
    }
}

__global__ __launch_bounds__(BLK) void yolo_final(
    const float* __restrict__ partial, float* __restrict__ out) {
    __shared__ double sm[BLK][6];
    double a[6] = {0, 0, 0, 0, 0, 0};
    for (int i = threadIdx.x; i < G1; i += BLK) {
        #pragma unroll
        for (int k = 0; k < 6; ++k) a[k] += (double)partial[i * 6 + k];
    }
    #pragma unroll
    for (int k = 0; k < 6; ++k) sm[threadIdx.x][k] = a[k];
    __syncthreads();
    for (int off = BLK / 2; off > 0; off >>= 1) {
        if (threadIdx.x < off) {
            #pragma unroll
            for (int k = 0; k < 6; ++k) sm[threadIdx.x][k] += sm[threadIdx.x + off][k];
        }
        __syncthreads();
    }
    if (threadIdx.x == 0) {
        const double resp_sum  = sm[0][0];
        const double bce_sum   = sm[0][1];
        const double sqxy_sum  = sm[0][2];
        const double sqwh_sum  = sm[0][3];
        const double nll_sum   = sm[0][4];
        const double coord_sum = sm[0][5];
        const double cnt = fmax(resp_sum, 1.0);
        const double contain_loss = bce_sum / cnt;
        const double loc_loss = (sqxy_sum + sqwh_sum) / (2.0 * cnt);
        const double class_loss = nll_sum / fmax(coord_sum, 1.0);
        out[0] = (float)(class_loss + contain_loss + 5.0 * loc_loss);
    }
}

extern "C" void kernel_launch(void* const* d_in, const int* in_sizes, int n_in,
                              void* d_out, int out_size, void* d_ws, size_t ws_size,
                              hipStream_t stream) {
    const float* pred = (const float*)d_in[0];
    const float* targ = (const float*)d_in[1];
    float* partial = (float*)d_ws;   // G1*6 floats = 48 KiB

    yolo_partial<<<G1, BLK, 0, stream>>>(pred, targ, partial);
    yolo_final<<<1, BLK, 0, stream>>>(partial, (float*)d_out);
}

// Round 4
// 49.029 us; speedup vs baseline: 1.1623x; 1.1623x over previous
//
#include <hip/hip_runtime.h>
#include <math.h>

#define NCELL (32768 * 49)   // 1,605,632
#define NE 30
#define NC 20                // classes
#define G1 1568              // 1568 * 1024 == NCELL exactly (no tail)
#define BLK 256
#define CPB 1024             // contiguous cells per block

// partial layout per block: [resp_sum, bce_sum, sqxy_sum, sqwh_sum, nll_sum, coord_sum]

__device__ __forceinline__ void process_cell(
    const float* __restrict__ pred, const float* __restrict__ targ, int cell,
    float& a0, float& a1, float& a2, float& a3, float& a4, float& a5) {

    const float2* p2 = reinterpret_cast<const float2*>(pred + (size_t)cell * NE);
    const float2* t2 = reinterpret_cast<const float2*>(targ + (size_t)cell * NE);

    float p[30], t[12];
    #pragma unroll
    for (int i = 0; i < 15; ++i) { float2 v = p2[i]; p[2*i] = v.x; p[2*i+1] = v.y; }
    #pragma unroll
    for (int i = 0; i < 6; ++i)  { float2 v = t2[i]; t[2*i] = v.x; t[2*i+1] = v.y; }

    // 2x2 cross IoU between pred boxes (rows) and target boxes (cols)
    float iou[2][2];
    #pragma unroll
    for (int i = 0; i < 2; ++i) {
        const float pcx = p[5*i], pcy = p[5*i+1], pw = p[5*i+2], ph = p[5*i+3];
        const float alx = pcx - pw*0.5f, aly = pcy - ph*0.5f;
        const float ahx = pcx + pw*0.5f, ahy = pcy + ph*0.5f;
        const float area_a = pw * ph;
        #pragma unroll
        for (int j = 0; j < 2; ++j) {
            const float tcx = t[5*j], tcy = t[5*j+1], tw = t[5*j+2], th = t[5*j+3];
            const float blx = tcx - tw*0.5f, bly = tcy - th*0.5f;
            const float bhx = tcx + tw*0.5f, bhy = tcy + th*0.5f;
            float ix = fminf(ahx, bhx) - fmaxf(alx, blx);
            float iy = fminf(ahy, bhy) - fmaxf(aly, bly);
            ix = fmaxf(ix, 0.f); iy = fmaxf(iy, 0.f);
            const float inter = ix * iy;
            const float area_b = tw * th;
            iou[i][j] = inter / (area_a + area_b - inter + 1e-12f);
        }
    }
    // argmax over pred-box axis, first-occurrence tie break (index 0)
    const int idx0 = (iou[1][0] > iou[0][0]) ? 1 : 0;
    const int idx1 = (iou[1][1] > iou[0][1]) ? 1 : 0;

    #pragma unroll
    for (int k = 0; k < 2; ++k) {
        const bool resp = (idx0 == k || idx1 == k);
        if (resp) {
            a0 += 1.f;
            const float cp = p[5*k+4], ct = t[5*k+4];
            // logaddexp(0, cp) - cp*ct  (stable)
            a1 += fmaxf(cp, 0.f) + log1pf(expf(-fabsf(cp))) - cp * ct;
            const float dx = p[5*k]   - t[5*k];
            const float dy = p[5*k+1] - t[5*k+1];
            a2 += dx*dx + dy*dy;
            const float dw = p[5*k+2] - t[5*k+2];
            const float dh = p[5*k+3] - t[5*k+3];
            a3 += dw*dw + dh*dh;
        }
    }

    a5 += 1.f;
    // class index: clip(floor(t10), 0, 19)  (clip in float, then cast)
    const float cf = fminf(fmaxf(floorf(t[10]), 0.f), 19.f);
    const int cls = (int)cf;
    float m = p[10];
    #pragma unroll
    for (int c = 1; c < NC; ++c) m = fmaxf(m, p[10 + c]);
    float se = 0.f;
    float sel = 0.f;   // p[10+cls] via static-index select (no scratch)
    #pragma unroll
    for (int c = 0; c < NC; ++c) {
        se += expf(p[10 + c] - m);
        sel += (c == cls) ? p[10 + c] : 0.f;
    }
    a4 += -(sel - m - logf(se));
}

__global__ __launch_bounds__(BLK) void yolo_partial(
    const float* __restrict__ pred,
    const float* __restrict__ targ,
    float* __restrict__ partial) {

    const int base = blockIdx.x * CPB;
    const int tid  = threadIdx.x;
    const int wave = tid >> 6;
    const int lane = tid & 63;

    // --- scan phase: 4 t4 loads per thread, all issued upfront ---
    float t4v[4];
    #pragma unroll
    for (int k = 0; k < 4; ++k)
        t4v[k] = targ[(size_t)(base + k * BLK + tid) * NE + 4];

    // --- ballot-compact coord cells into per-wave LDS segments ---
    // (deterministic: fixed ballot -> prefix order, no atomics)
    __shared__ int s_idx[4][256];   // per-wave segment, max 4*64 entries
    __shared__ int s_cnt[4];
    int cnt = 0;
    #pragma unroll
    for (int k = 0; k < 4; ++k) {
        const bool c = t4v[k] > 0.f;
        const unsigned long long m = __ballot(c);
        const int pre = __popcll(m & ((1ull << lane) - 1ull));
        if (c) s_idx[wave][cnt + pre] = k * BLK + tid;  // block-local cell idx
        cnt += __popcll(m);
    }
    if (lane == 0) s_cnt[wave] = cnt;
    __syncthreads();

    const int c0 = s_cnt[0], c1 = s_cnt[1], c2 = s_cnt[2], c3 = s_cnt[3];
    const int total = c0 + c1 + c2 + c3;   // ~84 avg of 1024

    float a0 = 0.f, a1 = 0.f, a2 = 0.f, a3 = 0.f, a4 = 0.f, a5 = 0.f;

    // --- dense heavy pass: ~1 iteration, only ceil(total/256) wave-passes ---
    for (int i = tid; i < total; i += BLK) {
        int j = i, w = 0;
        if (j >= c0) { j -= c0; w = 1;
            if (j >= c1) { j -= c1; w = 2;
                if (j >= c2) { j -= c2; w = 3; } } }
        const int loc = s_idx[w][j];
        process_cell(pred, targ, base + loc, a0, a1, a2, a3, a4, a5);
    }

    // --- wave (64-lane) tree reduction ---
    #pragma unroll
    for (int off = 32; off > 0; off >>= 1) {
        a0 += __shfl_down(a0, off, 64);
        a1 += __shfl_down(a1, off, 64);
        a2 += __shfl_down(a2, off, 64);
        a3 += __shfl_down(a3, off, 64);
        a4 += __shfl_down(a4, off, 64);
        a5 += __shfl_down(a5, off, 64);
    }

    __shared__ float sm[4][6];  // 4 waves per 256-thread block
    if (lane == 0) {
        sm[wave][0] = a0; sm[wave][1] = a1; sm[wave][2] = a2;
        sm[wave][3] = a3; sm[wave][4] = a4; sm[wave][5] = a5;
    }
    __syncthreads();
    if (tid == 0) {
        #pragma unroll
        for (int k = 0; k < 6; ++k) {
            // fixed-order sum over the 4 waves -> deterministic
            float s = sm[0][k] + sm[1][k] + sm[2][k] + sm[3][k];
            partial[blockIdx.x * 6 + k] = s;
        }
    }
}

__global__ __launch_bounds__(BLK) void yolo_final(
    const float* __restrict__ partial, float* __restrict__ out) {
    __shared__ double sm[BLK][6];
    double a[6] = {0, 0, 0, 0, 0, 0};
    for (int i = threadIdx.x; i < G1; i += BLK) {
        #pragma unroll
        for (int k = 0; k < 6; ++k) a[k] += (double)partial[i * 6 + k];
    }
    #pragma unroll
    for (int k = 0; k < 6; ++k) sm[threadIdx.x][k] = a[k];
    __syncthreads();
    for (int off = BLK / 2; off > 0; off >>= 1) {
        if (threadIdx.x < off) {
            #pragma unroll
            for (int k = 0; k < 6; ++k) sm[threadIdx.x][k] += sm[threadIdx.x + off][k];
        }
        __syncthreads();
    }
    if (threadIdx.x == 0) {
        const double resp_sum  = sm[0][0];
        const double bce_sum   = sm[0][1];
        const double sqxy_sum  = sm[0][2];
        const double sqwh_sum  = sm[0][3];
        const double nll_sum   = sm[0][4];
        const double coord_sum = sm[0][5];
        const double cnt = fmax(resp_sum, 1.0);
        const double contain_loss = bce_sum / cnt;
        const double loc_loss = (sqxy_sum + sqwh_sum) / (2.0 * cnt);
        const double class_loss = nll_sum / fmax(coord_sum, 1.0);
        out[0] = (float)(class_loss + contain_loss + 5.0 * loc_loss);
    }
}

extern "C" void kernel_launch(void* const* d_in, const int* in_sizes, int n_in,
                              void* d_out, int out_size, void* d_ws, size_t ws_size,
                              hipStream_t stream) {
    const float* pred = (const float*)d_in[0];
    const float* targ = (const float*)d_in[1];
    float* partial = (float*)d_ws;   // G1*6 floats

    yolo_partial<<<G1, BLK, 0, stream>>>(pred, targ, partial);
    yolo_final<<<1, BLK, 0, stream>>>(partial, (float*)d_out);
}